// Round 4
// baseline (606.527 us; speedup 1.0000x reference)
//
#include <hip/hip_runtime.h>
#include <hip/hip_cooperative_groups.h>

namespace cg = cooperative_groups;

typedef unsigned short u16;
typedef unsigned int   u32;

#define NQd 10000
#define NSd 500
#define Bd  32
#define Sd  200
#define Td  199   // S-1
#define Dd  128
#define NR  6368  // Bd*Td

typedef __attribute__((ext_vector_type(8))) short bf16x8;
typedef __attribute__((ext_vector_type(4))) float f32x4;

__device__ __forceinline__ float sigf(float x) { return 1.f / (1.f + __expf(-x)); }
__device__ __forceinline__ float bf2f(u16 u) { return __uint_as_float(((u32)u) << 16); }
__device__ __forceinline__ u16 f2bf(float f) {            // round-to-nearest-even
  u32 b = __float_as_uint(f);
  b += 0x7FFFu + ((b >> 16) & 1u);
  return (u16)(b >> 16);
}
__device__ __forceinline__ void unp2(u32 u, float &a, float &b) {
  a = __uint_as_float(u << 16);
  b = __uint_as_float(u & 0xffff0000u);
}
__device__ __forceinline__ void unpack16(uint4 a0, uint4 a1, float* f) {
  unp2(a0.x, f[0], f[1]);  unp2(a0.y, f[2], f[3]);
  unp2(a0.z, f[4], f[5]);  unp2(a0.w, f[6], f[7]);
  unp2(a1.x, f[8], f[9]);  unp2(a1.y, f[10], f[11]);
  unp2(a1.z, f[12], f[13]); unp2(a1.w, f[14], f[15]);
}

struct Args {
  const int *question, *response, *q_nb, *s_nb, *qs_sk;
  const float *emb_q, *emb_s, *emb_r;
  const float *W_ih, *b_ih, *b_hh, *ft_W, *ft_b, *agg_W, *agg_b, *last_W, *last_b;
  const float *q_W, *q_b, *k_W, *k_b, *w_W;
  u16 *tabA, *tabB, *tabC, *tabs1, *tabs2, *G, *states, *embq_bf, *embs_bf, *wts, *wiht;
  float *a_state, *qw, *kw, *scal, *er_part;
  int *qid_map, *resp_map;
};

// LDS: 21760 u16 = 43,520 B.  Wl/Ql = [0,17408) u16; Al/Sl = [17408, 21760).
#define SMEM_U16 21760

// ---------------------------------------------------------------------------
// one 32-row x 128-col MFMA GEMM tile: out = act(in @ Wt^T + bias)
// ---------------------------------------------------------------------------
__device__ __forceinline__ void gemm_tile(
    const u16* __restrict__ Atab, const u16* __restrict__ Btab,
    const int* __restrict__ nbr, int K, const int* __restrict__ rowmap,
    const u16* __restrict__ Wt,           // bf16 [col][128], pre-offset
    const float* __restrict__ cbias,
    const float* __restrict__ rbias, const int* __restrict__ rbias_idx, int rb_off,
    u16* __restrict__ out, int rows, int act, int tile0, int tid, u16* smem)
{
  u16* Wl = smem;
  u16* Al = smem + 17408;
  for (int i = tid; i < 2048; i += 256) {
    int col = i >> 4, seg = i & 15;
    *(uint4*)&Wl[col * 136 + seg * 8] = *(const uint4*)&Wt[(long)col * 128 + seg * 8];
  }
  {
    int r = tid & 31, k0 = (tid >> 5) * 16;
    int row = tile0 + r; if (row >= rows) row = rows - 1;
    int arow = rowmap ? rowmap[row] : row;
    const u16* ap = Atab + (long)arow * 128 + k0;
    if (K == 0) {
      *(uint4*)&Al[r * 136 + k0]     = *(const uint4*)ap;
      *(uint4*)&Al[r * 136 + k0 + 8] = *(const uint4*)(ap + 8);
    } else {
      float f[16];
      unpack16(*(const uint4*)ap, *(const uint4*)(ap + 8), f);
      float s[16];
#pragma unroll
      for (int q = 0; q < 16; ++q) s[q] = 0.f;
      for (int l = 0; l < K; ++l) {
        int id = nbr[(long)arow * K + l];
        const u16* np = Btab + (long)id * 128 + k0;
        float g[16];
        unpack16(*(const uint4*)np, *(const uint4*)(np + 8), g);
#pragma unroll
        for (int q = 0; q < 16; ++q) s[q] += g[q];
      }
      float inv = 1.f / (float)K;
#pragma unroll
      for (int q = 0; q < 16; ++q) f[q] += s[q] * inv;
      u32 p[8];
#pragma unroll
      for (int q = 0; q < 8; ++q)
        p[q] = (u32)f2bf(f[2 * q]) | ((u32)f2bf(f[2 * q + 1]) << 16);
      *(uint4*)&Al[r * 136 + k0]     = make_uint4(p[0], p[1], p[2], p[3]);
      *(uint4*)&Al[r * 136 + k0 + 8] = make_uint4(p[4], p[5], p[6], p[7]);
    }
  }
  __syncthreads();

  const int lane = tid & 63, wv = tid >> 6;
  const int l15 = lane & 15, quad = lane >> 4;
  const int cw = wv * 32;
  f32x4 acc[2][2];
#pragma unroll
  for (int a = 0; a < 2; ++a)
#pragma unroll
    for (int bb = 0; bb < 2; ++bb) acc[a][bb] = (f32x4){0.f, 0.f, 0.f, 0.f};
#pragma unroll
  for (int kc = 0; kc < 4; ++kc) {
    const int ko = kc * 32 + quad * 8;
    bf16x8 af[2], bfv[2];
    af[0]  = *(const bf16x8*)&Al[l15 * 136 + ko];
    af[1]  = *(const bf16x8*)&Al[(16 + l15) * 136 + ko];
    bfv[0] = *(const bf16x8*)&Wl[(cw + l15) * 136 + ko];
    bfv[1] = *(const bf16x8*)&Wl[(cw + 16 + l15) * 136 + ko];
#pragma unroll
    for (int mt = 0; mt < 2; ++mt)
#pragma unroll
      for (int nt = 0; nt < 2; ++nt)
        acc[mt][nt] = __builtin_amdgcn_mfma_f32_16x16x32_bf16(af[mt], bfv[nt], acc[mt][nt], 0, 0, 0);
  }
#pragma unroll
  for (int nt = 0; nt < 2; ++nt) {
    int col = cw + nt * 16 + l15;
    float cb = (rbias == nullptr) ? cbias[col] : 0.f;
#pragma unroll
    for (int mt = 0; mt < 2; ++mt) {
      int rbase = tile0 + mt * 16 + quad * 4;
#pragma unroll
      for (int i = 0; i < 4; ++i) {
        int row = rbase + i;
        if (row >= rows) continue;
        float bias = (rbias != nullptr)
                   ? rbias[(long)rbias_idx[row] * 512 + rb_off + col] : cb;
        float v = acc[mt][nt][i] + bias;
        if (act == 0) v = tanhf(v);
        else if (act == 1) v = fmaxf(v, 0.f);
        out[(long)row * 128 + col] = f2bf(v);
      }
    }
  }
}

// ---------------------------------------------------------------------------
// fused gates (i,g,o) + LSTM pointwise + a_state, one 32-row tile
// ---------------------------------------------------------------------------
__device__ __forceinline__ void gates_tile(const Args& a, int tile0, int tid, u16* smem)
{
  u16* Wl = smem;
  u16* Al = smem + 17408;
  {
    int r = tid & 31, k0 = (tid >> 5) * 16;
    int row = tile0 + r;                       // NR divisible by 32: always valid
    int arow = a.qid_map[row];
    const u16* ap = a.tabC + (long)arow * 128 + k0;
    *(uint4*)&Al[r * 136 + k0]     = *(const uint4*)ap;
    *(uint4*)&Al[r * 136 + k0 + 8] = *(const uint4*)(ap + 8);
  }
  const int lane = tid & 63, wv = tid >> 6;
  const int l15 = lane & 15, quad = lane >> 4;
  const int cw = wv * 32;
  f32x4 acc[3][2][2];
  const int goff[3] = {0, 256, 384};
#pragma unroll
  for (int p = 0; p < 3; ++p) {
    __syncthreads();   // p=0: guard Al; p>0: guard Wl overwrite vs prior MFMA reads
    for (int i = tid; i < 2048; i += 256) {
      int col = i >> 4, seg = i & 15;
      *(uint4*)&Wl[col * 136 + seg * 8] =
          *(const uint4*)&a.wiht[((long)(goff[p] + col)) * 128 + seg * 8];
    }
    __syncthreads();
#pragma unroll
    for (int mt = 0; mt < 2; ++mt)
#pragma unroll
      for (int nt = 0; nt < 2; ++nt) acc[p][mt][nt] = (f32x4){0.f, 0.f, 0.f, 0.f};
#pragma unroll
    for (int kc = 0; kc < 4; ++kc) {
      const int ko = kc * 32 + quad * 8;
      bf16x8 af[2], bfv[2];
      af[0]  = *(const bf16x8*)&Al[l15 * 136 + ko];
      af[1]  = *(const bf16x8*)&Al[(16 + l15) * 136 + ko];
      bfv[0] = *(const bf16x8*)&Wl[(cw + l15) * 136 + ko];
      bfv[1] = *(const bf16x8*)&Wl[(cw + 16 + l15) * 136 + ko];
#pragma unroll
      for (int mt = 0; mt < 2; ++mt)
#pragma unroll
        for (int nt = 0; nt < 2; ++nt)
          acc[p][mt][nt] = __builtin_amdgcn_mfma_f32_16x16x32_bf16(af[mt], bfv[nt], acc[p][mt][nt], 0, 0, 0);
    }
  }
  __syncthreads();
  float* hb = (float*)Wl;    // [32][132] f32 = 16.9 KB, fits Wl region
#pragma unroll
  for (int nt = 0; nt < 2; ++nt) {
    int colL = cw + nt * 16 + l15;
#pragma unroll
    for (int mt = 0; mt < 2; ++mt) {
#pragma unroll
      for (int i = 0; i < 4; ++i) {
        int rL = mt * 16 + quad * 4 + i;
        int row = tile0 + rL;
        const float* rb = a.er_part + (long)a.resp_map[row] * 512;
        float iv = acc[0][mt][nt][i] + rb[colL];
        float gv = acc[1][mt][nt][i] + rb[256 + colL];
        float ov = acc[2][mt][nt][i] + rb[384 + colL];
        float c = sigf(iv) * tanhf(gv);
        float h = sigf(ov) * tanhf(c);
        a.states[(long)row * 128 + colL] = f2bf(h);
        hb[rL * 132 + colL] = h;
      }
    }
  }
  __syncthreads();
#pragma unroll
  for (int rr = 0; rr < 8; ++rr) {
    int rL = wv * 8 + rr;
    float p = hb[rL * 132 + lane] * a.qw[lane] + hb[rL * 132 + 64 + lane] * a.qw[64 + lane];
#pragma unroll
    for (int off = 32; off > 0; off >>= 1) p += __shfl_xor(p, off);
    if (lane == 0) a.a_state[tile0 + rL] = p + a.scal[0];
  }
}

// ---------------------------------------------------------------------------
// g_mfma tile: G[b][col][n] = sigmoid(states . qs_vec), 32 n x 128 col
// ---------------------------------------------------------------------------
__device__ __forceinline__ void g_tile(const Args& a, int b, int c0, int n0, int tid, u16* smem)
{
  u16* Ql = smem;
  u16* Sl = smem + 17408;
  {
    int r = tid & 31, k0 = (tid >> 5) * 16;
    int n = n0 + r; if (n > 198) n = 198;
    const u16* sp = a.states + ((long)b * Td + n) * 128 + k0;
    *(uint4*)&Sl[r * 136 + k0]     = *(const uint4*)sp;
    *(uint4*)&Sl[r * 136 + k0 + 8] = *(const uint4*)(sp + 8);
  }
  {
    int j = tid >> 1, k0 = (tid & 1) * 64;
    int col = c0 + j;
    uint4* dst = (uint4*)&Ql[j * 136 + k0];
    if (col < 995) {
      int t = col / 5, m = col - t * 5;
      int qn = a.question[b * Sd + t + 1];
      const u16* src = (m == 0) ? a.embq_bf + (long)qn * 128
                                : a.embs_bf + (long)a.qs_sk[qn * 4 + (m - 1)] * 128;
      src += k0;
#pragma unroll
      for (int q = 0; q < 8; ++q) dst[q] = ((const uint4*)src)[q];
    } else {
      uint4 z = make_uint4(0, 0, 0, 0);
#pragma unroll
      for (int q = 0; q < 8; ++q) dst[q] = z;
    }
  }
  __syncthreads();
  const int lane = tid & 63, wv = tid >> 6;
  const int l15 = lane & 15, quad = lane >> 4;
  const int cw = wv * 32;
  f32x4 acc[2][2];
#pragma unroll
  for (int x = 0; x < 2; ++x)
#pragma unroll
    for (int y = 0; y < 2; ++y) acc[x][y] = (f32x4){0.f, 0.f, 0.f, 0.f};
#pragma unroll
  for (int kc = 0; kc < 4; ++kc) {
    const int ko = kc * 32 + quad * 8;
    bf16x8 af[2], bfv[2];
    af[0]  = *(const bf16x8*)&Sl[l15 * 136 + ko];
    af[1]  = *(const bf16x8*)&Sl[(16 + l15) * 136 + ko];
    bfv[0] = *(const bf16x8*)&Ql[(cw + l15) * 136 + ko];
    bfv[1] = *(const bf16x8*)&Ql[(cw + 16 + l15) * 136 + ko];
#pragma unroll
    for (int mt = 0; mt < 2; ++mt)
#pragma unroll
      for (int nt = 0; nt < 2; ++nt)
        acc[mt][nt] = __builtin_amdgcn_mfma_f32_16x16x32_bf16(af[mt], bfv[nt], acc[mt][nt], 0, 0, 0);
  }
#pragma unroll
  for (int nt = 0; nt < 2; ++nt) {
    int col = c0 + cw + nt * 16 + l15;
    if (col >= 995) continue;
#pragma unroll
    for (int mt = 0; mt < 2; ++mt) {
      int nb = n0 + mt * 16 + quad * 4;
      if (nb > 196) continue;
      u32 lo = (u32)f2bf(sigf(acc[mt][nt][0])) | ((u32)f2bf(sigf(acc[mt][nt][1])) << 16);
      u32 hi = (u32)f2bf(sigf(acc[mt][nt][2])) | ((u32)f2bf(sigf(acc[mt][nt][3])) << 16);
      *(uint2*)&a.G[((long)b * 1000 + col) * 200 + nb] = make_uint2(lo, hi);
    }
  }
}

// ---------------------------------------------------------------------------
// pred item (b,t) with inline pm softmax
// ---------------------------------------------------------------------------
__device__ __forceinline__ void pred_item(const Args& a, int item, int tid, u16* smem,
                                          float* __restrict__ out)
{
  float* sred = (float*)smem;
  float* am   = sred + 256;
  float* pmv  = sred + 264;
  int b = item / Td, t = item - b * Td;

  float v = (tid <= t) ? a.a_state[b * Td + tid] : -1e30f;
  sred[tid] = v; __syncthreads();
  for (int s = 128; s > 0; s >>= 1) { if (tid < s) sred[tid] = fmaxf(sred[tid], sred[tid + s]); __syncthreads(); }
  float amax = sred[0]; __syncthreads();
  float ev = (tid <= t) ? __expf(v - amax) : 0.f;
  sred[tid] = ev; __syncthreads();
  for (int s = 128; s > 0; s >>= 1) { if (tid < s) sred[tid] += sred[tid + s]; __syncthreads(); }
  float Z = sred[0]; __syncthreads();

  int qn = a.question[b * Sd + t + 1];
  if (tid < 160) {
    int m = tid >> 5, j = tid & 31;
    const u16* src = (m == 0) ? a.embq_bf + (long)qn * 128
                              : a.embs_bf + (long)a.qs_sk[qn * 4 + (m - 1)] * 128;
    float p = 0.f;
#pragma unroll
    for (int c = 0; c < 128; c += 32) p += bf2f(src[c + j]) * a.kw[c + j];
#pragma unroll
    for (int off = 16; off > 0; off >>= 1) p += __shfl_xor(p, off);
    if (j == 0) am[m] = p + a.scal[1];
  }
  __syncthreads();
  if (tid == 0) {
    float mx = am[0];
    for (int m = 1; m < 5; ++m) mx = fmaxf(mx, am[m]);
    float e[5], z = 0.f;
    for (int m = 0; m < 5; ++m) { e[m] = __expf(am[m] - mx); z += e[m]; }
    float iz = 1.f / z;
    for (int m = 0; m < 5; ++m) pmv[m] = e[m] * iz;
  }
  __syncthreads();
  float accv = 0.f;
  if (tid <= t) {
    long base = ((long)b * 1000 + (long)t * 5) * 200 + tid;
    accv = ev * (pmv[0] * bf2f(a.G[base])       + pmv[1] * bf2f(a.G[base + 200]) +
                 pmv[2] * bf2f(a.G[base + 400]) + pmv[3] * bf2f(a.G[base + 600]) +
                 pmv[4] * bf2f(a.G[base + 800]));
  }
  sred[tid] = accv; __syncthreads();
  for (int s = 128; s > 0; s >>= 1) { if (tid < s) sred[tid] += sred[tid + s]; __syncthreads(); }
  if (tid == 0) {
    out[b * Sd + t + 1] = sred[0] / Z;
    if (t == 0) out[b * Sd] = 0.f;
  }
  __syncthreads();
}

// ---------------------------------------------------------------------------
// stage dispatcher (block-stride over items; any grid size is correct)
// ---------------------------------------------------------------------------
__device__ void run_stage(const Args& a, float* out, int stage, int bid, int nB, int tid, u16* smem)
{
  switch (stage) {
    case 0: {  // prep: bf16 conversions, transposed weights, maps, small dots
      const int T = nB * 256;
      for (int i = bid * 256 + tid; i < 491106; i += T) {
        if (i < 320000) {
          float4 v = *(const float4*)&a.emb_q[(long)i * 4];
          ((uint2*)a.embq_bf)[i] = make_uint2(
              (u32)f2bf(v.x) | ((u32)f2bf(v.y) << 16),
              (u32)f2bf(v.z) | ((u32)f2bf(v.w) << 16));
        } else if (i < 336000) {
          int c = i - 320000;
          float4 v = *(const float4*)&a.emb_s[(long)c * 4];
          ((uint2*)a.embs_bf)[c] = make_uint2(
              (u32)f2bf(v.x) | ((u32)f2bf(v.y) << 16),
              (u32)f2bf(v.z) | ((u32)f2bf(v.w) << 16));
        } else if (i < 417920) {
          int e = i - 336000;
          int seg = e >> 14, r = e & 16383;
          int col = r >> 7, k = r & 127;
          const float* src = (seg < 3) ? (a.agg_W + seg * 16384)
                                       : (seg == 3 ? a.last_W : a.ft_W);
          a.wts[e] = f2bf(src[k * 128 + col]);
        } else if (i < 483456) {
          int e = i - 417920;
          int col = e >> 7, k = e & 127;
          a.wiht[e] = f2bf(a.W_ih[k * 512 + col]);
        } else if (i < 489824) {
          int j = i - 483456;
          int b = j / Td, s = j - b * Td;
          a.qid_map[j]  = a.question[b * Sd + s];
          a.resp_map[j] = a.response[b * Sd + s];
        } else {
          int s = i - 489824;
          if (s < 128) {
            float acc = 0;
            for (int e = 0; e < 128; ++e) acc += a.q_W[s * 128 + e] * a.w_W[e];
            a.qw[s] = acc;
          } else if (s < 256) {
            int d = s - 128; float acc = 0;
            for (int e = 0; e < 128; ++e) acc += a.k_W[d * 128 + e] * a.w_W[128 + e];
            a.kw[d] = acc;
          } else if (s == 256) {
            float acc = 0;
            for (int e = 0; e < 128; ++e) acc += a.q_b[e] * a.w_W[e];
            a.scal[0] = acc;
          } else if (s == 257) {
            float acc = 0;
            for (int e = 0; e < 128; ++e) acc += a.k_b[e] * a.w_W[128 + e];
            a.scal[1] = acc;
          } else {
            int e2 = s - 258, rr = e2 >> 9, col = e2 & 511;
            float acc = a.b_ih[col] + a.b_hh[col];
            for (int d = 0; d < 128; ++d) acc += a.emb_r[rr * Dd + d] * a.W_ih[(128 + d) * 512 + col];
            a.er_part[rr * 512 + col] = acc;
          }
        }
      }
      break;
    }
    case 1:  // hop0: f2(313) | f1(16) | f0(313)
      for (int i = bid; i < 642; i += nB) {
        if (i < 313)
          gemm_tile(a.embq_bf, a.embs_bf, a.q_nb, 4, nullptr, a.wts + 2 * 16384,
                    a.agg_b + 256, nullptr, nullptr, 0, a.tabA, NQd, 0, i * 32, tid, smem);
        else if (i < 329)
          gemm_tile(a.embs_bf, a.embq_bf, a.s_nb, 10, nullptr, a.wts + 16384,
                    a.agg_b + 128, nullptr, nullptr, 0, a.tabs1, NSd, 0, (i - 313) * 32, tid, smem);
        else
          gemm_tile(a.embq_bf, a.embs_bf, a.q_nb, 4, nullptr, a.wts,
                    a.agg_b, nullptr, nullptr, 0, a.tabB, NQd, 0, (i - 329) * 32, tid, smem);
        __syncthreads();
      }
      break;
    case 2:  // hop1: g1(16) | g0(313)
      for (int i = bid; i < 329; i += nB) {
        if (i < 16)
          gemm_tile(a.tabs1, a.tabA, a.s_nb, 10, nullptr, a.wts + 16384,
                    a.agg_b + 128, nullptr, nullptr, 0, a.tabs2, NSd, 0, i * 32, tid, smem);
        else
          gemm_tile(a.tabB, a.tabs1, a.q_nb, 4, nullptr, a.wts,
                    a.agg_b, nullptr, nullptr, 0, a.tabC, NQd, 0, (i - 16) * 32, tid, smem);
        __syncthreads();
      }
      break;
    case 3:  // h0
      for (int i = bid; i < 313; i += nB) {
        gemm_tile(a.tabC, a.tabs2, a.q_nb, 4, nullptr, a.wts,
                  a.agg_b, nullptr, nullptr, 0, a.tabA, NQd, 0, i * 32, tid, smem);
        __syncthreads();
      }
      break;
    case 4:  // agg = tanh(h0 @ last_W + last_b)
      for (int i = bid; i < 313; i += nB) {
        gemm_tile(a.tabA, nullptr, nullptr, 0, nullptr, a.wts + 3 * 16384,
                  a.last_b, nullptr, nullptr, 0, a.tabB, NQd, 0, i * 32, tid, smem);
        __syncthreads();
      }
      break;
    case 5:  // qt = relu(agg @ ft_W + ft_b)
      for (int i = bid; i < 313; i += nB) {
        gemm_tile(a.tabB, nullptr, nullptr, 0, nullptr, a.wts + 4 * 16384,
                  a.ft_b, nullptr, nullptr, 0, a.tabC, NQd, 1, i * 32, tid, smem);
        __syncthreads();
      }
      break;
    case 6:  // gates + LSTM + a_state (199 tiles)
      for (int i = bid; i < 199; i += nB) {
        gates_tile(a, i * 32, tid, smem);
        __syncthreads();
      }
      break;
    case 7:  // g_mfma: 32 b x 8 cy x 8 nx, skip upper-triangle tiles
      for (int i = bid; i < 2048; i += nB) {
        int b = i >> 6, cy = (i >> 3) & 7, nx = i & 7;
        int c0 = cy * 128, n0 = nx * 32;
        int c_hi = c0 + 127; if (c_hi > 994) c_hi = 994;
        if (n0 <= c_hi / 5) {
          g_tile(a, b, c0, n0, tid, smem);
        }
        __syncthreads();
      }
      break;
    case 8:  // pred
      for (int i = bid; i < NR; i += nB) pred_item(a, i, tid, smem, out);
      break;
  }
}

__global__ void __launch_bounds__(256, 3) mega(Args a, float* out)
{
  __shared__ __align__(16) u16 smem[SMEM_U16];
  cg::grid_group grid = cg::this_grid();
  const int tid = threadIdx.x, bid = blockIdx.x, nB = gridDim.x;
#pragma unroll 1
  for (int s = 0; s < 9; ++s) {
    run_stage(a, out, s, bid, nB, tid, smem);
    if (s < 8) grid.sync();
  }
}

__global__ void __launch_bounds__(256, 3) stage_kern(Args a, float* out, int stage)
{
  __shared__ __align__(16) u16 smem[SMEM_U16];
  run_stage(a, out, stage, blockIdx.x, gridDim.x, threadIdx.x, smem);
}

// ---------------------------------------------------------------------------
extern "C" void kernel_launch(void* const* d_in, const int* in_sizes, int n_in,
                              void* d_out, int out_size, void* d_ws, size_t ws_size,
                              hipStream_t stream)
{
  Args a;
  a.question = (const int*)d_in[0];
  a.response = (const int*)d_in[1];
  a.q_nb     = (const int*)d_in[3];
  a.s_nb     = (const int*)d_in[4];
  a.qs_sk    = (const int*)d_in[5];
  a.emb_q    = (const float*)d_in[6];
  a.emb_s    = (const float*)d_in[7];
  a.emb_r    = (const float*)d_in[8];
  a.W_ih     = (const float*)d_in[9];
  a.b_ih     = (const float*)d_in[10];
  a.b_hh     = (const float*)d_in[11];
  a.ft_W     = (const float*)d_in[12];
  a.ft_b     = (const float*)d_in[13];
  a.agg_W    = (const float*)d_in[14];
  a.agg_b    = (const float*)d_in[15];
  a.last_W   = (const float*)d_in[16];
  a.last_b   = (const float*)d_in[17];
  a.q_W      = (const float*)d_in[18];
  a.q_b      = (const float*)d_in[19];
  a.k_W      = (const float*)d_in[20];
  a.k_b      = (const float*)d_in[21];
  a.w_W      = (const float*)d_in[22];

  u16* wsu = (u16*)d_ws;
  const long NT = 1280000, ST = 64000, RT = (long)NR * Dd;
  a.tabA  = wsu;                 // [0, 1.28M)
  a.tabB  = a.tabA + NT;
  a.tabC  = a.tabB + NT;
  a.tabs1 = a.tabC + NT;
  a.tabs2 = a.tabs1 + ST;        // ends 3,968,000
  a.G     = wsu;                 // [0, 6.4M) overlays tabs (dead before stage 7)
  a.states  = wsu + 6400000;     // RT
  a.embq_bf = a.states + RT;
  a.embs_bf = a.embq_bf + NT;
  a.wts     = a.embs_bf + ST;    // 5*16384
  a.wiht    = a.wts + 5 * 16384; // 65536
  float* fp = (float*)(a.wiht + 65536);
  a.a_state = fp;                // 6368
  a.qw      = fp + 6368;
  a.kw      = fp + 6496;
  a.scal    = fp + 6624;         // 16
  a.er_part = fp + 6640;         // 1024
  a.qid_map  = (int*)(fp + 7664);
  a.resp_map = a.qid_map + NR;

  float* out = (float*)d_out;

  int occ = 0;
  hipError_t qe = hipOccupancyMaxActiveBlocksPerMultiprocessor(&occ, (const void*)mega, 256, 0);
  if (qe != hipSuccess || occ < 1) occ = 1;
  if (occ > 3) occ = 3;
  dim3 grid(occ * 256), block(256);
  void* kargs[2] = {(void*)&a, (void*)&out};
  hipError_t e = hipLaunchCooperativeKernel((const void*)mega, grid, block, kargs, 0, stream);
  if (e != hipSuccess) {
    (void)hipGetLastError();  // clear, fall back to serial stage launches
    const int grids[9] = {640, 642, 329, 313, 313, 313, 199, 1024, 1024};
    for (int s = 0; s < 9; ++s)
      stage_kern<<<grids[s], 256, 0, stream>>>(a, out, s);
  }
}

// Round 5
// 205.590 us; speedup vs baseline: 2.9502x; 2.9502x over previous
//
#include <hip/hip_runtime.h>

typedef unsigned short u16;
typedef unsigned int   u32;

#define NQd 10000
#define NSd 500
#define Bd  32
#define Sd  200
#define Td  199   // S-1
#define Dd  128
#define NR  6368  // Bd*Td

typedef __attribute__((ext_vector_type(8))) short bf16x8;
typedef __attribute__((ext_vector_type(4))) float f32x4;

__device__ __forceinline__ float sigf(float x) { return 1.f / (1.f + __expf(-x)); }
__device__ __forceinline__ float bf2f(u16 u) { return __uint_as_float(((u32)u) << 16); }
__device__ __forceinline__ u16 f2bf(float f) {            // round-to-nearest-even
  u32 b = __float_as_uint(f);
  b += 0x7FFFu + ((b >> 16) & 1u);
  return (u16)(b >> 16);
}
__device__ __forceinline__ void unp2(u32 u, float &a, float &b) {
  a = __uint_as_float(u << 16);
  b = __uint_as_float(u & 0xffff0000u);
}
__device__ __forceinline__ void unpack16(uint4 a0, uint4 a1, float* f) {
  unp2(a0.x, f[0], f[1]);  unp2(a0.y, f[2], f[3]);
  unp2(a0.z, f[4], f[5]);  unp2(a0.w, f[6], f[7]);
  unp2(a1.x, f[8], f[9]);  unp2(a1.y, f[10], f[11]);
  unp2(a1.z, f[12], f[13]); unp2(a1.w, f[14], f[15]);
}

struct Args {
  const int *question, *response, *q_nb, *s_nb, *qs_sk;
  const float *emb_q, *emb_s, *emb_r;
  const float *W_ih, *b_ih, *b_hh, *ft_W, *ft_b, *agg_W, *agg_b, *last_W, *last_b;
  const float *q_W, *q_b, *k_W, *k_b, *w_W;
  u16 *tabA, *tabB, *tabC, *tabs1, *tabs2, *G, *states, *embq_bf, *embs_bf, *wts, *wiht;
  float *a_state, *qw, *kw, *scal, *er_part;
  int *qid_map, *resp_map;
};

// LDS: 21760 u16 = 43,520 B.  Wl = [0,17408) u16; Al = [17408, 21760).
#define SMEM_U16 21760

// 16 MFMA accumulating a 32x128 tile: A rows in Al[r][k], B cols in Wl[c][k]
__device__ __forceinline__ void mfma_accum(const u16* Al, const u16* Wl,
                                           int l15, int quad, int cw, f32x4 acc[2][2])
{
#pragma unroll
  for (int kc = 0; kc < 4; ++kc) {
    const int ko = kc * 32 + quad * 8;
    bf16x8 af[2], bfv[2];
    af[0]  = *(const bf16x8*)&Al[l15 * 136 + ko];
    af[1]  = *(const bf16x8*)&Al[(16 + l15) * 136 + ko];
    bfv[0] = *(const bf16x8*)&Wl[(cw + l15) * 136 + ko];
    bfv[1] = *(const bf16x8*)&Wl[(cw + 16 + l15) * 136 + ko];
#pragma unroll
    for (int mt = 0; mt < 2; ++mt)
#pragma unroll
      for (int nt = 0; nt < 2; ++nt)
        acc[mt][nt] = __builtin_amdgcn_mfma_f32_16x16x32_bf16(af[mt], bfv[nt], acc[mt][nt], 0, 0, 0);
  }
}

__device__ __forceinline__ void zero_acc(f32x4 acc[2][2]) {
#pragma unroll
  for (int x = 0; x < 2; ++x)
#pragma unroll
    for (int y = 0; y < 2; ++y) acc[x][y] = (f32x4){0.f, 0.f, 0.f, 0.f};
}

// stage one 32-row gathered input tile into Al (bf16), K = neighbor count
__device__ __forceinline__ void stage_A(const u16* Atab, const u16* Btab,
                                        const int* nbr, int K, int tile0, int rows,
                                        int tid, u16* Al)
{
  int r = tid & 31, k0 = (tid >> 5) * 16;
  int row = tile0 + r; if (row >= rows) row = rows - 1;
  const u16* ap = Atab + (long)row * 128 + k0;
  if (K == 0) {
    *(uint4*)&Al[r * 136 + k0]     = *(const uint4*)ap;
    *(uint4*)&Al[r * 136 + k0 + 8] = *(const uint4*)(ap + 8);
  } else {
    float f[16];
    unpack16(*(const uint4*)ap, *(const uint4*)(ap + 8), f);
    float s[16];
#pragma unroll
    for (int q = 0; q < 16; ++q) s[q] = 0.f;
    for (int l = 0; l < K; ++l) {
      int id = nbr[(long)row * K + l];
      const u16* np = Btab + (long)id * 128 + k0;
      float g[16];
      unpack16(*(const uint4*)np, *(const uint4*)(np + 8), g);
#pragma unroll
      for (int q = 0; q < 16; ++q) s[q] += g[q];
    }
    float inv = 1.f / (float)K;
#pragma unroll
    for (int q = 0; q < 16; ++q) f[q] += s[q] * inv;
    u32 p[8];
#pragma unroll
    for (int q = 0; q < 8; ++q)
      p[q] = (u32)f2bf(f[2 * q]) | ((u32)f2bf(f[2 * q + 1]) << 16);
    *(uint4*)&Al[r * 136 + k0]     = make_uint4(p[0], p[1], p[2], p[3]);
    *(uint4*)&Al[r * 136 + k0 + 8] = make_uint4(p[4], p[5], p[6], p[7]);
  }
}

__device__ __forceinline__ void stage_W(const u16* Wt, int tid, u16* Wl)
{
  for (int i = tid; i < 2048; i += 256) {
    int col = i >> 4, seg = i & 15;
    *(uint4*)&Wl[col * 136 + seg * 8] = *(const uint4*)&Wt[(long)col * 128 + seg * 8];
  }
}

// full 32x128 GEMM tile: out = tanh(in @ Wt^T + cbias)
__device__ __forceinline__ void gemm_tile(
    const u16* __restrict__ Atab, const u16* __restrict__ Btab,
    const int* __restrict__ nbr, int K,
    const u16* __restrict__ Wt, const float* __restrict__ cbias,
    u16* __restrict__ out, int rows, int tile0, int tid, u16* smem)
{
  u16* Wl = smem;
  u16* Al = smem + 17408;
  stage_W(Wt, tid, Wl);
  stage_A(Atab, Btab, nbr, K, tile0, rows, tid, Al);
  __syncthreads();
  const int lane = tid & 63, wv = tid >> 6;
  const int l15 = lane & 15, quad = lane >> 4, cw = wv * 32;
  f32x4 acc[2][2];
  zero_acc(acc);
  mfma_accum(Al, Wl, l15, quad, cw, acc);
#pragma unroll
  for (int nt = 0; nt < 2; ++nt) {
    int col = cw + nt * 16 + l15;
    float cb = cbias[col];
#pragma unroll
    for (int mt = 0; mt < 2; ++mt) {
      int rbase = tile0 + mt * 16 + quad * 4;
#pragma unroll
      for (int i = 0; i < 4; ++i) {
        int row = rbase + i;
        if (row >= rows) continue;
        out[(long)row * 128 + col] = f2bf(tanhf(acc[mt][nt][i] + cb));
      }
    }
  }
}

// ---------------------------------------------------------------------------
// prep_all: bf16 emb copies, transposed bf16 weights, maps, small dots
// ---------------------------------------------------------------------------
__global__ __launch_bounds__(256) void prep_all(Args a)
{
  const int T = gridDim.x * 256;
  for (int i = blockIdx.x * 256 + threadIdx.x; i < 491106; i += T) {
    if (i < 320000) {
      float4 v = *(const float4*)&a.emb_q[(long)i * 4];
      ((uint2*)a.embq_bf)[i] = make_uint2(
          (u32)f2bf(v.x) | ((u32)f2bf(v.y) << 16),
          (u32)f2bf(v.z) | ((u32)f2bf(v.w) << 16));
    } else if (i < 336000) {
      int c = i - 320000;
      float4 v = *(const float4*)&a.emb_s[(long)c * 4];
      ((uint2*)a.embs_bf)[c] = make_uint2(
          (u32)f2bf(v.x) | ((u32)f2bf(v.y) << 16),
          (u32)f2bf(v.z) | ((u32)f2bf(v.w) << 16));
    } else if (i < 417920) {
      int e = i - 336000;
      int seg = e >> 14, r = e & 16383;
      int col = r >> 7, k = r & 127;
      const float* src = (seg < 3) ? (a.agg_W + seg * 16384)
                                   : (seg == 3 ? a.last_W : a.ft_W);
      a.wts[e] = f2bf(src[k * 128 + col]);
    } else if (i < 483456) {
      int e = i - 417920;
      int col = e >> 7, k = e & 127;
      a.wiht[e] = f2bf(a.W_ih[k * 512 + col]);
    } else if (i < 489824) {
      int j = i - 483456;
      int b = j / Td, s = j - b * Td;
      a.qid_map[j]  = a.question[b * Sd + s];
      a.resp_map[j] = a.response[b * Sd + s];
    } else {
      int s = i - 489824;
      if (s < 128) {
        float acc = 0;
        for (int e = 0; e < 128; ++e) acc += a.q_W[s * 128 + e] * a.w_W[e];
        a.qw[s] = acc;
      } else if (s < 256) {
        int d = s - 128; float acc = 0;
        for (int e = 0; e < 128; ++e) acc += a.k_W[d * 128 + e] * a.w_W[128 + e];
        a.kw[d] = acc;
      } else if (s == 256) {
        float acc = 0;
        for (int e = 0; e < 128; ++e) acc += a.q_b[e] * a.w_W[e];
        a.scal[0] = acc;
      } else if (s == 257) {
        float acc = 0;
        for (int e = 0; e < 128; ++e) acc += a.k_b[e] * a.w_W[128 + e];
        a.scal[1] = acc;
      } else {
        int e2 = s - 258, rr = e2 >> 9, col = e2 & 511;
        float acc = a.b_ih[col] + a.b_hh[col];
        for (int d = 0; d < 128; ++d) acc += a.emb_r[rr * Dd + d] * a.W_ih[(128 + d) * 512 + col];
        a.er_part[rr * 512 + col] = acc;
      }
    }
  }
}

// level1: f2 (313) | f1 (16) | f0 (313) — 642 blocks
__global__ __launch_bounds__(256) void level1(Args a)
{
  __shared__ __align__(16) u16 smem[SMEM_U16];
  const int i = blockIdx.x, tid = threadIdx.x;
  if (i < 313)
    gemm_tile(a.embq_bf, a.embs_bf, a.q_nb, 4, a.wts + 2 * 16384,
              a.agg_b + 256, a.tabA, NQd, i * 32, tid, smem);
  else if (i < 329)
    gemm_tile(a.embs_bf, a.embq_bf, a.s_nb, 10, a.wts + 16384,
              a.agg_b + 128, a.tabs1, NSd, (i - 313) * 32, tid, smem);
  else
    gemm_tile(a.embq_bf, a.embs_bf, a.q_nb, 4, a.wts,
              a.agg_b, a.tabB, NQd, (i - 329) * 32, tid, smem);
}

// level2: g1 (16) | g0 (313) — 329 blocks
__global__ __launch_bounds__(256) void level2(Args a)
{
  __shared__ __align__(16) u16 smem[SMEM_U16];
  const int i = blockIdx.x, tid = threadIdx.x;
  if (i < 16)
    gemm_tile(a.tabs1, a.tabA, a.s_nb, 10, a.wts + 16384,
              a.agg_b + 128, a.tabs2, NSd, i * 32, tid, smem);
  else
    gemm_tile(a.tabB, a.tabs1, a.q_nb, 4, a.wts,
              a.agg_b, a.tabC, NQd, (i - 16) * 32, tid, smem);
}

// chain3: h0 -> agg -> qt, all in-block; only qt hits global (tabA). 313 blocks.
__global__ __launch_bounds__(256) void chain3(Args a)
{
  __shared__ __align__(16) u16 smem[SMEM_U16];
  u16* Wl = smem;
  u16* Al = smem + 17408;
  const int tid = threadIdx.x;
  const int tile0 = blockIdx.x * 32;
  const int lane = tid & 63, wv = tid >> 6;
  const int l15 = lane & 15, quad = lane >> 4, cw = wv * 32;
  f32x4 acc[2][2];

  // phase 1: h0 = tanh((g0 + mean g1-nbrs) @ aggW0^T + agg_b)
  stage_W(a.wts, tid, Wl);
  stage_A(a.tabC, a.tabs2, a.q_nb, 4, tile0, NQd, tid, Al);
  __syncthreads();
  zero_acc(acc);
  mfma_accum(Al, Wl, l15, quad, cw, acc);
  __syncthreads();   // all reads of Al/Wl done
#pragma unroll
  for (int nt = 0; nt < 2; ++nt) {
    int col = cw + nt * 16 + l15;
    float cb = a.agg_b[col];
#pragma unroll
    for (int mt = 0; mt < 2; ++mt)
#pragma unroll
      for (int i = 0; i < 4; ++i) {
        int rL = mt * 16 + quad * 4 + i;
        Al[rL * 136 + col] = f2bf(tanhf(acc[mt][nt][i] + cb));
      }
  }
  stage_W(a.wts + 3 * 16384, tid, Wl);   // lastt
  __syncthreads();

  // phase 2: agg = tanh(h0 @ last_W + last_b)
  zero_acc(acc);
  mfma_accum(Al, Wl, l15, quad, cw, acc);
  __syncthreads();
#pragma unroll
  for (int nt = 0; nt < 2; ++nt) {
    int col = cw + nt * 16 + l15;
    float cb = a.last_b[col];
#pragma unroll
    for (int mt = 0; mt < 2; ++mt)
#pragma unroll
      for (int i = 0; i < 4; ++i) {
        int rL = mt * 16 + quad * 4 + i;
        Al[rL * 136 + col] = f2bf(tanhf(acc[mt][nt][i] + cb));
      }
  }
  stage_W(a.wts + 4 * 16384, tid, Wl);   // ftt
  __syncthreads();

  // phase 3: qt = relu(agg @ ft_W + ft_b) -> tabA (global)
  zero_acc(acc);
  mfma_accum(Al, Wl, l15, quad, cw, acc);
#pragma unroll
  for (int nt = 0; nt < 2; ++nt) {
    int col = cw + nt * 16 + l15;
    float cb = a.ft_b[col];
#pragma unroll
    for (int mt = 0; mt < 2; ++mt) {
      int rbase = tile0 + mt * 16 + quad * 4;
#pragma unroll
      for (int i = 0; i < 4; ++i) {
        int row = rbase + i;
        if (row >= NQd) continue;
        a.tabA[(long)row * 128 + col] = f2bf(fmaxf(acc[mt][nt][i] + cb, 0.f));
      }
    }
  }
}

// gates (i,g,o) + LSTM pointwise + a_state. 199 blocks x 32 rows.
__global__ __launch_bounds__(256) void gates_k(Args a)
{
  __shared__ __align__(16) u16 smem[SMEM_U16];
  u16* Wl = smem;
  u16* Al = smem + 17408;
  const int tid = threadIdx.x;
  const int tile0 = blockIdx.x * 32;
  {
    int r = tid & 31, k0 = (tid >> 5) * 16;
    int row = tile0 + r;                       // NR divisible by 32
    int arow = a.qid_map[row];
    const u16* ap = a.tabA + (long)arow * 128 + k0;
    *(uint4*)&Al[r * 136 + k0]     = *(const uint4*)ap;
    *(uint4*)&Al[r * 136 + k0 + 8] = *(const uint4*)(ap + 8);
  }
  const int lane = tid & 63, wv = tid >> 6;
  const int l15 = lane & 15, quad = lane >> 4, cw = wv * 32;
  f32x4 acc[3][2][2];
  const int goff[3] = {0, 256, 384};
#pragma unroll
  for (int p = 0; p < 3; ++p) {
    __syncthreads();   // p=0: guard Al; p>0: guard Wl overwrite vs prior MFMA reads
    stage_W(a.wiht + (long)goff[p] * 128, tid, Wl);
    __syncthreads();
    zero_acc(acc[p]);
    mfma_accum(Al, Wl, l15, quad, cw, acc[p]);
  }
  __syncthreads();
  float* hb = (float*)Wl;    // [32][132] f32, fits Wl region
#pragma unroll
  for (int nt = 0; nt < 2; ++nt) {
    int colL = cw + nt * 16 + l15;
#pragma unroll
    for (int mt = 0; mt < 2; ++mt) {
#pragma unroll
      for (int i = 0; i < 4; ++i) {
        int rL = mt * 16 + quad * 4 + i;
        int row = tile0 + rL;
        const float* rb = a.er_part + (long)a.resp_map[row] * 512;
        float iv = acc[0][mt][nt][i] + rb[colL];
        float gv = acc[1][mt][nt][i] + rb[256 + colL];
        float ov = acc[2][mt][nt][i] + rb[384 + colL];
        float c = sigf(iv) * tanhf(gv);
        float h = sigf(ov) * tanhf(c);
        a.states[(long)row * 128 + colL] = f2bf(h);
        hb[rL * 132 + colL] = h;
      }
    }
  }
  __syncthreads();
#pragma unroll
  for (int rr = 0; rr < 8; ++rr) {
    int rL = wv * 8 + rr;
    float p = hb[rL * 132 + lane] * a.qw[lane] + hb[rL * 132 + 64 + lane] * a.qw[64 + lane];
#pragma unroll
    for (int off = 32; off > 0; off >>= 1) p += __shfl_xor(p, off);
    if (lane == 0) a.a_state[tile0 + rL] = p + a.scal[0];
  }
}

// g_k: G[b][col][n] = sigmoid(states . qs_vec), tile 32 n x 128 col
__global__ __launch_bounds__(256) void g_k(Args a)
{
  const int n0 = blockIdx.x * 32;
  const int c0 = blockIdx.y * 128;
  const int b  = blockIdx.z;
  int c_hi = c0 + 127; if (c_hi > 994) c_hi = 994;
  if (n0 > c_hi / 5) return;  // tile entirely n > t: never read

  __shared__ __align__(16) u16 smem[SMEM_U16];
  u16* Ql = smem;
  u16* Sl = smem + 17408;
  const int tid = threadIdx.x;
  {
    int r = tid & 31, k0 = (tid >> 5) * 16;
    int n = n0 + r; if (n > 198) n = 198;
    const u16* sp = a.states + ((long)b * Td + n) * 128 + k0;
    *(uint4*)&Sl[r * 136 + k0]     = *(const uint4*)sp;
    *(uint4*)&Sl[r * 136 + k0 + 8] = *(const uint4*)(sp + 8);
  }
  {
    int j = tid >> 1, k0 = (tid & 1) * 64;
    int col = c0 + j;
    uint4* dst = (uint4*)&Ql[j * 136 + k0];
    if (col < 995) {
      int t = col / 5, m = col - t * 5;
      int qn = a.question[b * Sd + t + 1];
      const u16* src = (m == 0) ? a.embq_bf + (long)qn * 128
                                : a.embs_bf + (long)a.qs_sk[qn * 4 + (m - 1)] * 128;
      src += k0;
#pragma unroll
      for (int q = 0; q < 8; ++q) dst[q] = ((const uint4*)src)[q];
    } else {
      uint4 z = make_uint4(0, 0, 0, 0);
#pragma unroll
      for (int q = 0; q < 8; ++q) dst[q] = z;
    }
  }
  __syncthreads();
  const int lane = tid & 63, wv = tid >> 6;
  const int l15 = lane & 15, quad = lane >> 4, cw = wv * 32;
  f32x4 acc[2][2];
  zero_acc(acc);
  mfma_accum(Sl, Ql, l15, quad, cw, acc);
#pragma unroll
  for (int nt = 0; nt < 2; ++nt) {
    int col = c0 + cw + nt * 16 + l15;
    if (col >= 995) continue;
#pragma unroll
    for (int mt = 0; mt < 2; ++mt) {
      int nb = n0 + mt * 16 + quad * 4;
      if (nb > 196) continue;
      u32 lo = (u32)f2bf(sigf(acc[mt][nt][0])) | ((u32)f2bf(sigf(acc[mt][nt][1])) << 16);
      u32 hi = (u32)f2bf(sigf(acc[mt][nt][2])) | ((u32)f2bf(sigf(acc[mt][nt][3])) << 16);
      *(uint2*)&a.G[((long)b * 1000 + col) * 200 + nb] = make_uint2(lo, hi);
    }
  }
}

// pred: one (b,t) per block, inline pm softmax
__global__ __launch_bounds__(256) void pred_k(Args a, float* __restrict__ out)
{
  __shared__ float sred[256];
  __shared__ float am[8];
  __shared__ float pmv[8];
  const int item = blockIdx.x;
  const int b = item / Td, t = item - b * Td;
  const int tid = threadIdx.x;

  float v = (tid <= t) ? a.a_state[b * Td + tid] : -1e30f;
  sred[tid] = v; __syncthreads();
  for (int s = 128; s > 0; s >>= 1) { if (tid < s) sred[tid] = fmaxf(sred[tid], sred[tid + s]); __syncthreads(); }
  float amax = sred[0]; __syncthreads();
  float ev = (tid <= t) ? __expf(v - amax) : 0.f;
  sred[tid] = ev; __syncthreads();
  for (int s = 128; s > 0; s >>= 1) { if (tid < s) sred[tid] += sred[tid + s]; __syncthreads(); }
  float Z = sred[0]; __syncthreads();

  int qn = a.question[b * Sd + t + 1];
  if (tid < 160) {
    int m = tid >> 5, j = tid & 31;
    const u16* src = (m == 0) ? a.embq_bf + (long)qn * 128
                              : a.embs_bf + (long)a.qs_sk[qn * 4 + (m - 1)] * 128;
    float p = 0.f;
#pragma unroll
    for (int c = 0; c < 128; c += 32) p += bf2f(src[c + j]) * a.kw[c + j];
#pragma unroll
    for (int off = 16; off > 0; off >>= 1) p += __shfl_xor(p, off);
    if (j == 0) am[m] = p + a.scal[1];
  }
  __syncthreads();
  if (tid == 0) {
    float mx = am[0];
    for (int m = 1; m < 5; ++m) mx = fmaxf(mx, am[m]);
    float e[5], z = 0.f;
    for (int m = 0; m < 5; ++m) { e[m] = __expf(am[m] - mx); z += e[m]; }
    float iz = 1.f / z;
    for (int m = 0; m < 5; ++m) pmv[m] = e[m] * iz;
  }
  __syncthreads();
  float accv = 0.f;
  if (tid <= t) {
    long base = ((long)b * 1000 + (long)t * 5) * 200 + tid;
    accv = ev * (pmv[0] * bf2f(a.G[base])       + pmv[1] * bf2f(a.G[base + 200]) +
                 pmv[2] * bf2f(a.G[base + 400]) + pmv[3] * bf2f(a.G[base + 600]) +
                 pmv[4] * bf2f(a.G[base + 800]));
  }
  sred[tid] = accv; __syncthreads();
  for (int s = 128; s > 0; s >>= 1) { if (tid < s) sred[tid] += sred[tid + s]; __syncthreads(); }
  if (tid == 0) {
    out[b * Sd + t + 1] = sred[0] / Z;
    if (t == 0) out[b * Sd] = 0.f;
  }
}

// ---------------------------------------------------------------------------
extern "C" void kernel_launch(void* const* d_in, const int* in_sizes, int n_in,
                              void* d_out, int out_size, void* d_ws, size_t ws_size,
                              hipStream_t stream)
{
  Args a;
  a.question = (const int*)d_in[0];
  a.response = (const int*)d_in[1];
  a.q_nb     = (const int*)d_in[3];
  a.s_nb     = (const int*)d_in[4];
  a.qs_sk    = (const int*)d_in[5];
  a.emb_q    = (const float*)d_in[6];
  a.emb_s    = (const float*)d_in[7];
  a.emb_r    = (const float*)d_in[8];
  a.W_ih     = (const float*)d_in[9];
  a.b_ih     = (const float*)d_in[10];
  a.b_hh     = (const float*)d_in[11];
  a.ft_W     = (const float*)d_in[12];
  a.ft_b     = (const float*)d_in[13];
  a.agg_W    = (const float*)d_in[14];
  a.agg_b    = (const float*)d_in[15];
  a.last_W   = (const float*)d_in[16];
  a.last_b   = (const float*)d_in[17];
  a.q_W      = (const float*)d_in[18];
  a.q_b      = (const float*)d_in[19];
  a.k_W      = (const float*)d_in[20];
  a.k_b      = (const float*)d_in[21];
  a.w_W      = (const float*)d_in[22];

  u16* wsu = (u16*)d_ws;
  const long NT = 1280000, ST = 64000, RT = (long)NR * Dd;
  a.tabA  = wsu;                 // [0, 1.28M)
  a.tabB  = a.tabA + NT;
  a.tabC  = a.tabB + NT;
  a.tabs1 = a.tabC + NT;
  a.tabs2 = a.tabs1 + ST;        // ends 3,968,000
  a.G     = wsu;                 // [0, 6.4M) overlays tabs (tabA dead after gates_k)
  a.states  = wsu + 6400000;     // RT
  a.embq_bf = a.states + RT;
  a.embs_bf = a.embq_bf + NT;
  a.wts     = a.embs_bf + ST;    // 5*16384
  a.wiht    = a.wts + 5 * 16384; // 65536
  float* fp = (float*)(a.wiht + 65536);
  a.a_state = fp;                // 6368
  a.qw      = fp + 6368;
  a.kw      = fp + 6496;
  a.scal    = fp + 6624;         // 16
  a.er_part = fp + 6640;         // 1024
  a.qid_map  = (int*)(fp + 7664);
  a.resp_map = a.qid_map + NR;

  float* out = (float*)d_out;

  prep_all<<<640, 256, 0, stream>>>(a);
  level1<<<642, 256, 0, stream>>>(a);
  level2<<<329, 256, 0, stream>>>(a);
  chain3<<<313, 256, 0, stream>>>(a);
  gates_k<<<199, 256, 0, stream>>>(a);
  g_k<<<dim3(7, 8, Bd), 256, 0, stream>>>(a);
  pred_k<<<NR, 256, 0, stream>>>(a, out);
}

// Round 6
// 196.727 us; speedup vs baseline: 3.0831x; 1.0451x over previous
//
#include <hip/hip_runtime.h>

typedef unsigned short u16;
typedef unsigned int   u32;

#define NQd 10000
#define NSd 500
#define Bd  32
#define Sd  200
#define Td  199   // S-1
#define Dd  128
#define NR  6368  // Bd*Td
#define PB  208   // padded per-batch stride for ev/invZ/pm/pred_acc (mult of 4)

typedef __attribute__((ext_vector_type(8))) short bf16x8;
typedef __attribute__((ext_vector_type(4))) float f32x4;

__device__ __forceinline__ float sigf(float x) {
  return __builtin_amdgcn_rcpf(1.f + __expf(-x));
}
__device__ __forceinline__ float tanh_f(float x) {
  float ax = fminf(fabsf(x), 15.f);
  float e = __expf(2.f * ax);
  float r = 1.f - 2.f * __builtin_amdgcn_rcpf(e + 1.f);
  return copysignf(r, x);
}
__device__ __forceinline__ float bf2f(u16 u) { return __uint_as_float(((u32)u) << 16); }
__device__ __forceinline__ u16 f2bf(float f) {            // round-to-nearest-even
  u32 b = __float_as_uint(f);
  b += 0x7FFFu + ((b >> 16) & 1u);
  return (u16)(b >> 16);
}
__device__ __forceinline__ void unp2(u32 u, float &a, float &b) {
  a = __uint_as_float(u << 16);
  b = __uint_as_float(u & 0xffff0000u);
}
__device__ __forceinline__ void unpack16(uint4 a0, uint4 a1, float* f) {
  unp2(a0.x, f[0], f[1]);  unp2(a0.y, f[2], f[3]);
  unp2(a0.z, f[4], f[5]);  unp2(a0.w, f[6], f[7]);
  unp2(a1.x, f[8], f[9]);  unp2(a1.y, f[10], f[11]);
  unp2(a1.z, f[12], f[13]); unp2(a1.w, f[14], f[15]);
}

struct Args {
  const int *question, *response, *q_nb, *s_nb, *qs_sk;
  const float *emb_q, *emb_s, *emb_r;
  const float *W_ih, *b_ih, *b_hh, *ft_W, *ft_b, *agg_W, *agg_b, *last_W, *last_b;
  const float *q_W, *q_b, *k_W, *k_b, *w_W;
  u16 *tabA, *tabB, *tabC, *tabs1, *tabs2, *states, *embq_bf, *embs_bf, *wts, *wiht;
  float *a_state, *qw, *kw, *scal, *er_part, *ev, *invZ, *pred_acc, *pm;
  int *qid_map, *resp_map;
};

// LDS: 21760 u16 = 43,520 B.  Wl = [0,17408) u16; Al = [17408, 21760).
#define SMEM_U16 21760

__device__ __forceinline__ void mfma_accum(const u16* Al, const u16* Wl,
                                           int l15, int quad, int cw, f32x4 acc[2][2])
{
#pragma unroll
  for (int kc = 0; kc < 4; ++kc) {
    const int ko = kc * 32 + quad * 8;
    bf16x8 af[2], bfv[2];
    af[0]  = *(const bf16x8*)&Al[l15 * 136 + ko];
    af[1]  = *(const bf16x8*)&Al[(16 + l15) * 136 + ko];
    bfv[0] = *(const bf16x8*)&Wl[(cw + l15) * 136 + ko];
    bfv[1] = *(const bf16x8*)&Wl[(cw + 16 + l15) * 136 + ko];
#pragma unroll
    for (int mt = 0; mt < 2; ++mt)
#pragma unroll
      for (int nt = 0; nt < 2; ++nt)
        acc[mt][nt] = __builtin_amdgcn_mfma_f32_16x16x32_bf16(af[mt], bfv[nt], acc[mt][nt], 0, 0, 0);
  }
}

__device__ __forceinline__ void zero_acc(f32x4 acc[2][2]) {
#pragma unroll
  for (int x = 0; x < 2; ++x)
#pragma unroll
    for (int y = 0; y < 2; ++y) acc[x][y] = (f32x4){0.f, 0.f, 0.f, 0.f};
}

// stage one 32-row gathered input tile into Al (bf16), K = neighbor count
__device__ __forceinline__ void stage_A(const u16* Atab, const u16* Btab,
                                        const int* nbr, int K, int tile0, int rows,
                                        int tid, u16* Al)
{
  int r = tid & 31, k0 = (tid >> 5) * 16;
  int row = tile0 + r; if (row >= rows) row = rows - 1;
  const u16* ap = Atab + (long)row * 128 + k0;
  if (K == 0) {
    *(uint4*)&Al[r * 136 + k0]     = *(const uint4*)ap;
    *(uint4*)&Al[r * 136 + k0 + 8] = *(const uint4*)(ap + 8);
  } else {
    float f[16];
    unpack16(*(const uint4*)ap, *(const uint4*)(ap + 8), f);
    float s[16];
#pragma unroll
    for (int q = 0; q < 16; ++q) s[q] = 0.f;
    for (int l = 0; l < K; ++l) {
      int id = nbr[(long)row * K + l];
      const u16* np = Btab + (long)id * 128 + k0;
      float g[16];
      unpack16(*(const uint4*)np, *(const uint4*)(np + 8), g);
#pragma unroll
      for (int q = 0; q < 16; ++q) s[q] += g[q];
    }
    float inv = 1.f / (float)K;
#pragma unroll
    for (int q = 0; q < 16; ++q) f[q] += s[q] * inv;
    u32 p[8];
#pragma unroll
    for (int q = 0; q < 8; ++q)
      p[q] = (u32)f2bf(f[2 * q]) | ((u32)f2bf(f[2 * q + 1]) << 16);
    *(uint4*)&Al[r * 136 + k0]     = make_uint4(p[0], p[1], p[2], p[3]);
    *(uint4*)&Al[r * 136 + k0 + 8] = make_uint4(p[4], p[5], p[6], p[7]);
  }
}

__device__ __forceinline__ void stage_W(const u16* Wt, int tid, u16* Wl)
{
  for (int i = tid; i < 2048; i += 256) {
    int col = i >> 4, seg = i & 15;
    *(uint4*)&Wl[col * 136 + seg * 8] = *(const uint4*)&Wt[(long)col * 128 + seg * 8];
  }
}

// epilogue write: out[row][col] = f2bf(tanh_f(acc+cb)) to global
__device__ __forceinline__ void epi_tanh_global(const f32x4 acc[2][2], const float* cbias,
                                                u16* out, int rows, int tile0,
                                                int l15, int quad, int cw)
{
#pragma unroll
  for (int nt = 0; nt < 2; ++nt) {
    int col = cw + nt * 16 + l15;
    float cb = cbias[col];
#pragma unroll
    for (int mt = 0; mt < 2; ++mt) {
      int rbase = tile0 + mt * 16 + quad * 4;
#pragma unroll
      for (int i = 0; i < 4; ++i) {
        int row = rbase + i;
        if (row >= rows) continue;
        out[(long)row * 128 + col] = f2bf(tanh_f(acc[mt][nt][i] + cb));
      }
    }
  }
}

// full 32x128 GEMM tile: out = tanh(in @ Wt^T + cbias)
__device__ __forceinline__ void gemm_tile(
    const u16* __restrict__ Atab, const u16* __restrict__ Btab,
    const int* __restrict__ nbr, int K,
    const u16* __restrict__ Wt, const float* __restrict__ cbias,
    u16* __restrict__ out, int rows, int tile0, int tid, u16* smem)
{
  u16* Wl = smem;
  u16* Al = smem + 17408;
  stage_W(Wt, tid, Wl);
  stage_A(Atab, Btab, nbr, K, tile0, rows, tid, Al);
  __syncthreads();
  const int lane = tid & 63, wv = tid >> 6;
  const int l15 = lane & 15, quad = lane >> 4, cw = wv * 32;
  f32x4 acc[2][2];
  zero_acc(acc);
  mfma_accum(Al, Wl, l15, quad, cw, acc);
  epi_tanh_global(acc, cbias, out, rows, tile0, l15, quad, cw);
}

// ---------------------------------------------------------------------------
// prep_all: bf16 emb copies, transposed bf16 weights, maps, small dots
// ---------------------------------------------------------------------------
__global__ __launch_bounds__(256) void prep_all(Args a)
{
  const int T = gridDim.x * 256;
  for (int i = blockIdx.x * 256 + threadIdx.x; i < 491106; i += T) {
    if (i < 320000) {
      float4 v = *(const float4*)&a.emb_q[(long)i * 4];
      ((uint2*)a.embq_bf)[i] = make_uint2(
          (u32)f2bf(v.x) | ((u32)f2bf(v.y) << 16),
          (u32)f2bf(v.z) | ((u32)f2bf(v.w) << 16));
    } else if (i < 336000) {
      int c = i - 320000;
      float4 v = *(const float4*)&a.emb_s[(long)c * 4];
      ((uint2*)a.embs_bf)[c] = make_uint2(
          (u32)f2bf(v.x) | ((u32)f2bf(v.y) << 16),
          (u32)f2bf(v.z) | ((u32)f2bf(v.w) << 16));
    } else if (i < 417920) {
      int e = i - 336000;
      int seg = e >> 14, r = e & 16383;
      int col = r >> 7, k = r & 127;
      const float* src = (seg < 3) ? (a.agg_W + seg * 16384)
                                   : (seg == 3 ? a.last_W : a.ft_W);
      a.wts[e] = f2bf(src[k * 128 + col]);
    } else if (i < 483456) {
      int e = i - 417920;
      int col = e >> 7, k = e & 127;
      a.wiht[e] = f2bf(a.W_ih[k * 512 + col]);
    } else if (i < 489824) {
      int j = i - 483456;
      int b = j / Td, s = j - b * Td;
      a.qid_map[j]  = a.question[b * Sd + s];
      a.resp_map[j] = a.response[b * Sd + s];
    } else {
      int s = i - 489824;
      if (s < 128) {
        float acc = 0;
        for (int e = 0; e < 128; ++e) acc += a.q_W[s * 128 + e] * a.w_W[e];
        a.qw[s] = acc;
      } else if (s < 256) {
        int d = s - 128; float acc = 0;
        for (int e = 0; e < 128; ++e) acc += a.k_W[d * 128 + e] * a.w_W[128 + e];
        a.kw[d] = acc;
      } else if (s == 256) {
        float acc = 0;
        for (int e = 0; e < 128; ++e) acc += a.q_b[e] * a.w_W[e];
        a.scal[0] = acc;
      } else if (s == 257) {
        float acc = 0;
        for (int e = 0; e < 128; ++e) acc += a.k_b[e] * a.w_W[128 + e];
        a.scal[1] = acc;
      } else {
        int e2 = s - 258, rr = e2 >> 9, col = e2 & 511;
        float acc = a.b_ih[col] + a.b_hh[col];
        for (int d = 0; d < 128; ++d) acc += a.emb_r[rr * Dd + d] * a.W_ih[(128 + d) * 512 + col];
        a.er_part[rr * 512 + col] = acc;
      }
    }
  }
}

// level1m: blocks 0..312: f2 AND f0 from ONE gathered A-tile; 313..328: f1
__global__ __launch_bounds__(256) void level1m(Args a)
{
  __shared__ __align__(16) u16 smem[SMEM_U16];
  const int i = blockIdx.x, tid = threadIdx.x;
  if (i >= 313) {
    gemm_tile(a.embs_bf, a.embq_bf, a.s_nb, 10, a.wts + 16384,
              a.agg_b + 128, a.tabs1, NSd, (i - 313) * 32, tid, smem);
    return;
  }
  u16* Wl = smem;
  u16* Al = smem + 17408;
  const int tile0 = i * 32;
  const int lane = tid & 63, wv = tid >> 6;
  const int l15 = lane & 15, quad = lane >> 4, cw = wv * 32;
  f32x4 acc[2][2];
  // shared gather: emb_q[row] + mean emb_s[q_nb[row]]
  stage_W(a.wts + 2 * 16384, tid, Wl);       // aggW2^T
  stage_A(a.embq_bf, a.embs_bf, a.q_nb, 4, tile0, NQd, tid, Al);
  __syncthreads();
  zero_acc(acc);
  mfma_accum(Al, Wl, l15, quad, cw, acc);
  epi_tanh_global(acc, a.agg_b + 256, a.tabA, NQd, tile0, l15, quad, cw);  // f2
  __syncthreads();                           // all Wl reads done
  stage_W(a.wts, tid, Wl);                   // aggW0^T
  __syncthreads();
  zero_acc(acc);
  mfma_accum(Al, Wl, l15, quad, cw, acc);
  epi_tanh_global(acc, a.agg_b, a.tabB, NQd, tile0, l15, quad, cw);        // f0
}

// level2: g1 (16) | g0 (313) — 329 blocks
__global__ __launch_bounds__(256) void level2(Args a)
{
  __shared__ __align__(16) u16 smem[SMEM_U16];
  const int i = blockIdx.x, tid = threadIdx.x;
  if (i < 16)
    gemm_tile(a.tabs1, a.tabA, a.s_nb, 10, a.wts + 16384,
              a.agg_b + 128, a.tabs2, NSd, i * 32, tid, smem);
  else
    gemm_tile(a.tabB, a.tabs1, a.q_nb, 4, a.wts,
              a.agg_b, a.tabC, NQd, (i - 16) * 32, tid, smem);
}

// chain3: h0 -> agg -> qt in-block; only qt hits global (tabA). 313 blocks.
__global__ __launch_bounds__(256) void chain3(Args a)
{
  __shared__ __align__(16) u16 smem[SMEM_U16];
  u16* Wl = smem;
  u16* Al = smem + 17408;
  const int tid = threadIdx.x;
  const int tile0 = blockIdx.x * 32;
  const int lane = tid & 63, wv = tid >> 6;
  const int l15 = lane & 15, quad = lane >> 4, cw = wv * 32;
  f32x4 acc[2][2];

  // phase 1: h0 = tanh((g0 + mean g1-nbrs) @ aggW0^T + agg_b)
  stage_W(a.wts, tid, Wl);
  stage_A(a.tabC, a.tabs2, a.q_nb, 4, tile0, NQd, tid, Al);
  __syncthreads();
  zero_acc(acc);
  mfma_accum(Al, Wl, l15, quad, cw, acc);
  __syncthreads();
#pragma unroll
  for (int nt = 0; nt < 2; ++nt) {
    int col = cw + nt * 16 + l15;
    float cb = a.agg_b[col];
#pragma unroll
    for (int mt = 0; mt < 2; ++mt)
#pragma unroll
      for (int i = 0; i < 4; ++i) {
        int rL = mt * 16 + quad * 4 + i;
        Al[rL * 136 + col] = f2bf(tanh_f(acc[mt][nt][i] + cb));
      }
  }
  stage_W(a.wts + 3 * 16384, tid, Wl);   // lastt
  __syncthreads();

  // phase 2: agg = tanh(h0 @ last_W + last_b)
  zero_acc(acc);
  mfma_accum(Al, Wl, l15, quad, cw, acc);
  __syncthreads();
#pragma unroll
  for (int nt = 0; nt < 2; ++nt) {
    int col = cw + nt * 16 + l15;
    float cb = a.last_b[col];
#pragma unroll
    for (int mt = 0; mt < 2; ++mt)
#pragma unroll
      for (int i = 0; i < 4; ++i) {
        int rL = mt * 16 + quad * 4 + i;
        Al[rL * 136 + col] = f2bf(tanh_f(acc[mt][nt][i] + cb));
      }
  }
  stage_W(a.wts + 4 * 16384, tid, Wl);   // ftt
  __syncthreads();

  // phase 3: qt = relu(agg @ ft_W + ft_b) -> tabA
  zero_acc(acc);
  mfma_accum(Al, Wl, l15, quad, cw, acc);
#pragma unroll
  for (int nt = 0; nt < 2; ++nt) {
    int col = cw + nt * 16 + l15;
    float cb = a.ft_b[col];
#pragma unroll
    for (int mt = 0; mt < 2; ++mt) {
      int rbase = tile0 + mt * 16 + quad * 4;
#pragma unroll
      for (int i = 0; i < 4; ++i) {
        int row = rbase + i;
        if (row >= NQd) continue;
        a.tabA[(long)row * 128 + col] = f2bf(fmaxf(acc[mt][nt][i] + cb, 0.f));
      }
    }
  }
}

// gates (i,g,o) + LSTM pointwise + a_state. 199 blocks x 32 rows.
__global__ __launch_bounds__(256) void gates_k(Args a)
{
  __shared__ __align__(16) u16 smem[SMEM_U16];
  u16* Wl = smem;
  u16* Al = smem + 17408;
  const int tid = threadIdx.x;
  const int tile0 = blockIdx.x * 32;
  {
    int r = tid & 31, k0 = (tid >> 5) * 16;
    int row = tile0 + r;
    int arow = a.qid_map[row];
    const u16* ap = a.tabA + (long)arow * 128 + k0;
    *(uint4*)&Al[r * 136 + k0]     = *(const uint4*)ap;
    *(uint4*)&Al[r * 136 + k0 + 8] = *(const uint4*)(ap + 8);
  }
  const int lane = tid & 63, wv = tid >> 6;
  const int l15 = lane & 15, quad = lane >> 4, cw = wv * 32;
  f32x4 acc[3][2][2];
  const int goff[3] = {0, 256, 384};
#pragma unroll
  for (int p = 0; p < 3; ++p) {
    __syncthreads();
    stage_W(a.wiht + (long)goff[p] * 128, tid, Wl);
    __syncthreads();
    zero_acc(acc[p]);
    mfma_accum(Al, Wl, l15, quad, cw, acc[p]);
  }
  __syncthreads();
  float* hb = (float*)Wl;    // [32][132] f32
#pragma unroll
  for (int nt = 0; nt < 2; ++nt) {
    int colL = cw + nt * 16 + l15;
#pragma unroll
    for (int mt = 0; mt < 2; ++mt) {
#pragma unroll
      for (int i = 0; i < 4; ++i) {
        int rL = mt * 16 + quad * 4 + i;
        int row = tile0 + rL;
        const float* rb = a.er_part + (long)a.resp_map[row] * 512;
        float iv = acc[0][mt][nt][i] + rb[colL];
        float gv = acc[1][mt][nt][i] + rb[256 + colL];
        float ov = acc[2][mt][nt][i] + rb[384 + colL];
        float c = sigf(iv) * tanh_f(gv);
        float h = sigf(ov) * tanh_f(c);
        a.states[(long)row * 128 + colL] = f2bf(h);
        hb[rL * 132 + colL] = h;
      }
    }
  }
  __syncthreads();
#pragma unroll
  for (int rr = 0; rr < 8; ++rr) {
    int rL = wv * 8 + rr;
    float p = hb[rL * 132 + lane] * a.qw[lane] + hb[rL * 132 + 64 + lane] * a.qw[64 + lane];
#pragma unroll
    for (int off = 32; off > 0; off >>= 1) p += __shfl_xor(p, off);
    if (lane == 0) a.a_state[tile0 + rL] = p + a.scal[0];
  }
}

// ---------------------------------------------------------------------------
// bprep: per-batch softmax pieces. Block b: gmax -> ev, Z->invZ, pm softmax5,
// zero pred_acc. 32 blocks x 256 threads.
// ---------------------------------------------------------------------------
__global__ __launch_bounds__(256) void bprep(Args a)
{
  __shared__ float red[256];
  __shared__ float evl[256];
  __shared__ float kwl[128];
  const int b = blockIdx.x, tid = threadIdx.x;
  if (tid < 128) kwl[tid] = a.kw[tid];
  float v = (tid < Td) ? a.a_state[b * Td + tid] : -1e30f;
  red[tid] = v; __syncthreads();
  for (int s = 128; s > 0; s >>= 1) { if (tid < s) red[tid] = fmaxf(red[tid], red[tid + s]); __syncthreads(); }
  float gmax = red[0];
  float e = (tid < Td) ? __expf(v - gmax) : 0.f;
  evl[tid] = e;
  if (tid < Td) { a.ev[b * PB + tid] = e; a.pred_acc[b * PB + tid] = 0.f; }
  __syncthreads();
  if (tid < Td) {
    float Z = 0.f;
    for (int n = 0; n <= tid; ++n) Z += evl[n];
    a.invZ[b * PB + tid] = 1.f / Z;
    // pm softmax over 5 m's for (b, t=tid)
    int qn = a.question[b * Sd + tid + 1];
    float am[5];
#pragma unroll
    for (int m = 0; m < 5; ++m) {
      const u16* src = (m == 0) ? a.embq_bf + (long)qn * 128
                                : a.embs_bf + (long)a.qs_sk[qn * 4 + (m - 1)] * 128;
      float s = 0.f;
      for (int k = 0; k < 128; k += 8) {
        uint4 u = *(const uint4*)&src[k];
        float f[8];
        unp2(u.x, f[0], f[1]); unp2(u.y, f[2], f[3]);
        unp2(u.z, f[4], f[5]); unp2(u.w, f[6], f[7]);
#pragma unroll
        for (int q = 0; q < 8; ++q) s = fmaf(f[q], kwl[k + q], s);
      }
      am[m] = s + a.scal[1];
    }
    float mx = am[0];
#pragma unroll
    for (int m = 1; m < 5; ++m) mx = fmaxf(mx, am[m]);
    float ex[5], z = 0.f;
#pragma unroll
    for (int m = 0; m < 5; ++m) { ex[m] = __expf(am[m] - mx); z += ex[m]; }
    float iz = 1.f / z;
#pragma unroll
    for (int m = 0; m < 5; ++m) a.pm[((long)b * PB + tid) * 5 + m] = ex[m] * iz;
  }
}

// ---------------------------------------------------------------------------
// gk_pred: sigmoid(states.qs) * ev[n] * pm[t,m], reduced over (n<=t, m) into
// pred_acc[b,t] (G never materialized). Grid (7 nx, 8 cy, 32 b).
// ---------------------------------------------------------------------------
__global__ __launch_bounds__(256) void gk_pred(Args a)
{
  const int n0 = blockIdx.x * 32;
  const int c0 = blockIdx.y * 128;
  const int b  = blockIdx.z;
  int c_hi = c0 + 127; if (c_hi > 994) c_hi = 994;
  const int tmax = c_hi / 5, tmin = c0 / 5;
  if (n0 > tmax) return;

  __shared__ __align__(16) u16 smem[SMEM_U16];
  __shared__ float predl[32];
  u16* Ql = smem;
  u16* Sl = smem + 17408;
  const int tid = threadIdx.x;
  if (tid < 32) predl[tid] = 0.f;
  {
    int r = tid & 31, k0 = (tid >> 5) * 16;
    int n = n0 + r; if (n > 198) n = 198;
    const u16* sp = a.states + ((long)b * Td + n) * 128 + k0;
    *(uint4*)&Sl[r * 136 + k0]     = *(const uint4*)sp;
    *(uint4*)&Sl[r * 136 + k0 + 8] = *(const uint4*)(sp + 8);
  }
  {
    int j = tid >> 1, k0 = (tid & 1) * 64;
    int col = c0 + j;
    uint4* dst = (uint4*)&Ql[j * 136 + k0];
    if (col < 995) {
      int t = col / 5, m = col - t * 5;
      int qn = a.question[b * Sd + t + 1];
      const u16* src = (m == 0) ? a.embq_bf + (long)qn * 128
                                : a.embs_bf + (long)a.qs_sk[qn * 4 + (m - 1)] * 128;
      src += k0;
#pragma unroll
      for (int q = 0; q < 8; ++q) dst[q] = ((const uint4*)src)[q];
    } else {
      uint4 z = make_uint4(0, 0, 0, 0);
#pragma unroll
      for (int q = 0; q < 8; ++q) dst[q] = z;
    }
  }
  __syncthreads();
  const int lane = tid & 63, wv = tid >> 6;
  const int l15 = lane & 15, quad = lane >> 4, cw = wv * 32;
  f32x4 acc[2][2];
  zero_acc(acc);
  mfma_accum(Sl, Ql, l15, quad, cw, acc);

#pragma unroll
  for (int nt = 0; nt < 2; ++nt) {
    int col = c0 + cw + nt * 16 + l15;
    if (col >= 995) continue;
    int t = col / 5, m = col - t * 5;
    float pmv = a.pm[((long)b * PB + t) * 5 + m];
    float part = 0.f;
#pragma unroll
    for (int mt = 0; mt < 2; ++mt) {
      int nb = n0 + mt * 16 + quad * 4;
      if (nb > t) continue;
      float4 ev4 = *(const float4*)&a.ev[b * PB + nb];
      float evv[4] = {ev4.x, ev4.y, ev4.z, ev4.w};
#pragma unroll
      for (int i = 0; i < 4; ++i) {
        int n = nb + i;
        if (n > t || n > 198) continue;
        part += evv[i] * sigf(acc[mt][nt][i]);
      }
    }
    part *= pmv;
    if (part != 0.f) atomicAdd(&predl[t - tmin], part);
  }
  __syncthreads();
  const int tcnt = tmax - tmin + 1;
  if (tid < tcnt) {
    float pv = predl[tid];
    if (pv != 0.f) atomicAdd(&a.pred_acc[b * PB + tmin + tid], pv);
  }
}

// finalize: out[b,0]=0; out[b,t+1] = pred_acc[b,t] * invZ[b,t]
__global__ __launch_bounds__(256) void finalize(Args a, float* __restrict__ out)
{
  int i = blockIdx.x * 256 + threadIdx.x;
  if (i >= Bd * Sd) return;
  int b = i / Sd, s = i - b * Sd;
  out[i] = (s == 0) ? 0.f : a.pred_acc[b * PB + s - 1] * a.invZ[b * PB + s - 1];
}

// ---------------------------------------------------------------------------
extern "C" void kernel_launch(void* const* d_in, const int* in_sizes, int n_in,
                              void* d_out, int out_size, void* d_ws, size_t ws_size,
                              hipStream_t stream)
{
  Args a;
  a.question = (const int*)d_in[0];
  a.response = (const int*)d_in[1];
  a.q_nb     = (const int*)d_in[3];
  a.s_nb     = (const int*)d_in[4];
  a.qs_sk    = (const int*)d_in[5];
  a.emb_q    = (const float*)d_in[6];
  a.emb_s    = (const float*)d_in[7];
  a.emb_r    = (const float*)d_in[8];
  a.W_ih     = (const float*)d_in[9];
  a.b_ih     = (const float*)d_in[10];
  a.b_hh     = (const float*)d_in[11];
  a.ft_W     = (const float*)d_in[12];
  a.ft_b     = (const float*)d_in[13];
  a.agg_W    = (const float*)d_in[14];
  a.agg_b    = (const float*)d_in[15];
  a.last_W   = (const float*)d_in[16];
  a.last_b   = (const float*)d_in[17];
  a.q_W      = (const float*)d_in[18];
  a.q_b      = (const float*)d_in[19];
  a.k_W      = (const float*)d_in[20];
  a.k_b      = (const float*)d_in[21];
  a.w_W      = (const float*)d_in[22];

  u16* wsu = (u16*)d_ws;
  const long NT = 1280000, ST = 64000, RT = (long)NR * Dd;
  a.tabA  = wsu;                 // NT
  a.tabB  = a.tabA + NT;
  a.tabC  = a.tabB + NT;
  a.tabs1 = a.tabC + NT;         // ST
  a.tabs2 = a.tabs1 + ST;        // ST -> ends 3,968,000
  a.states  = a.tabs2 + ST;      // RT
  a.embq_bf = a.states + RT;     // NT
  a.embs_bf = a.embq_bf + NT;    // ST
  a.wts     = a.embs_bf + ST;    // 5*16384
  a.wiht    = a.wts + 5 * 16384; // 65536 -> total 6,274,560 u16 (16B-aligned end)
  float* fp = (float*)(a.wiht + 65536);
  a.a_state = fp;                       // 6368
  a.qw      = fp + 6368;                // 128
  a.kw      = fp + 6496;                // 128
  a.scal    = fp + 6624;                // 16
  a.er_part = fp + 6640;                // 1024 -> 7664 (16B aligned: 7664%4==0)
  a.ev       = fp + 7664;               // 32*208
  a.invZ     = a.ev + 32 * PB;
  a.pred_acc = a.invZ + 32 * PB;
  a.pm       = a.pred_acc + 32 * PB;    // 32*208*5
  a.qid_map  = (int*)(a.pm + 32 * PB * 5);
  a.resp_map = a.qid_map + NR;

  float* out = (float*)d_out;

  prep_all<<<640, 256, 0, stream>>>(a);
  level1m<<<329, 256, 0, stream>>>(a);
  level2<<<329, 256, 0, stream>>>(a);
  chain3<<<313, 256, 0, stream>>>(a);
  gates_k<<<199, 256, 0, stream>>>(a);
  bprep<<<Bd, 256, 0, stream>>>(a);
  gk_pred<<<dim3(7, 8, Bd), 256, 0, stream>>>(a);
  finalize<<<25, 256, 0, stream>>>(a, out);
}